// Round 4
// baseline (140.435 us; speedup 1.0000x reference)
//
#include <hip/hip_runtime.h>
#include <hip/hip_fp16.h>

// AggregationLayer: out[n, :] = mean over {e : segment_ids[e]==n} of src[gather_idx[e], :]
// N=100000, E=3200000, D=32 fp32. segment_ids SORTED.
//
// Kernel A (prep): segment boundaries (start[n]) + fp16 conversion of src into TWO
//   compact feature-half arrays hsrcA (features 0..15) and hsrcB (16..31), 3.2 MB each.
// Kernel B (main): XCD-aware feature split. Blocks on XCDs 0-3 (blockIdx%8<4) gather
//   from hsrcA, XCDs 4-7 from hsrcB -> each XCD's 4 MB L2 fully caches its 3.2 MB half
//   => random gather becomes ~all-L2-hit. 2-lane groups, 16 B loads, unroll x8,
//   fp32 accumulate, single write of the owned feature half.

constexpr int D = 32;
constexpr int HD = 16;                        // features per half
constexpr int GSZ = 2;                        // lanes per segment group (2 x 8 halfs = 16)
constexpr int BLOCK = 256;
constexpr int SEGS_PER_BLOCK = BLOCK / GSZ;   // 128 segments per block

typedef _Float16 half8 __attribute__((ext_vector_type(8)));

__global__ __launch_bounds__(BLOCK) void prep_kernel(
    const float* __restrict__ src,
    const int*   __restrict__ segid,
    int*         __restrict__ start,   // N+1 entries
    _Float16*    __restrict__ hsrcA,   // N*16 halfs (features 0..15)
    _Float16*    __restrict__ hsrcB,   // N*16 halfs (features 16..31)
    int E, int N)
{
    const int t = blockIdx.x * BLOCK + threadIdx.x;   // t in [0, >=E]

    // --- segment boundaries (one coalesced pass over segid) ---
    if (t <= E) {
        int s, p;
        if (t == E) { s = N; p = segid[E - 1]; }
        else        { s = segid[t]; p = (t == 0) ? -1 : segid[t - 1]; }
        for (int n = p + 1; n <= s; ++n) start[n] = t;   // usually 0 or 1 iters
    }

    // --- fp32 -> fp16 split copy: thread t<N does row t half A, t in [N,2N) half B ---
    if (t < 2 * N) {
        const int  row  = (t < N) ? t : t - N;
        const int  hoff = (t < N) ? 0 : HD;
        _Float16*  dst  = (t < N) ? hsrcA : hsrcB;
        const float* sp = src + (size_t)row * D + hoff;
        const float4 a = *(const float4*)(sp);
        const float4 b = *(const float4*)(sp + 4);
        const float4 c = *(const float4*)(sp + 8);
        const float4 d = *(const float4*)(sp + 12);
        half8 h0, h1;
        h0[0] = (_Float16)a.x; h0[1] = (_Float16)a.y; h0[2] = (_Float16)a.z; h0[3] = (_Float16)a.w;
        h0[4] = (_Float16)b.x; h0[5] = (_Float16)b.y; h0[6] = (_Float16)b.z; h0[7] = (_Float16)b.w;
        h1[0] = (_Float16)c.x; h1[1] = (_Float16)c.y; h1[2] = (_Float16)c.z; h1[3] = (_Float16)c.w;
        h1[4] = (_Float16)d.x; h1[5] = (_Float16)d.y; h1[6] = (_Float16)d.z; h1[7] = (_Float16)d.w;
        *(half8*)(dst + (size_t)row * HD)     = h0;
        *(half8*)(dst + (size_t)row * HD + 8) = h1;
    }
}

__global__ __launch_bounds__(BLOCK) void AggregationLayer_53051436040325_kernel(
    const _Float16* __restrict__ hsrcA,
    const _Float16* __restrict__ hsrcB,
    const int*      __restrict__ gidx,
    const int*      __restrict__ start,
    float*          __restrict__ out,
    int N, int nblkHalf)
{
    const int bid  = blockIdx.x;
    const int xcd  = bid & 7;                     // round-robin XCD heuristic
    const int hsel = xcd >> 2;                    // 0: features 0..15, 1: 16..31
    const int wblk = (bid >> 3) * 4 + (xcd & 3);  // block index within the half
    if (wblk >= nblkHalf) return;

    const int n   = wblk * SEGS_PER_BLOCK + (threadIdx.x >> 1);  // segment id
    const int sub = threadIdx.x & 1;                             // 8-feature slot
    if (n >= N) return;

    const int lo = start[n];
    const int hi = start[n + 1];

    const _Float16* sp = (hsel ? hsrcB : hsrcA) + sub * 8;

    float acc[8];
#pragma unroll
    for (int j = 0; j < 8; ++j) acc[j] = 0.f;

    int e = lo;
    // Unroll x8: 8 independent idx->gather dependent-load chains in flight.
    for (; e + 8 <= hi; e += 8) {
        int g[8];
#pragma unroll
        for (int k = 0; k < 8; ++k) g[k] = gidx[e + k];
        half8 v[8];
#pragma unroll
        for (int k = 0; k < 8; ++k) v[k] = *(const half8*)(sp + (size_t)g[k] * HD);
#pragma unroll
        for (int k = 0; k < 8; ++k)
#pragma unroll
            for (int j = 0; j < 8; ++j) acc[j] += (float)v[k][j];
    }
    for (; e < hi; ++e) {
        const half8 v = *(const half8*)(sp + (size_t)gidx[e] * HD);
#pragma unroll
        for (int j = 0; j < 8; ++j) acc[j] += (float)v[j];
    }

    const int c = hi - lo;
    const float inv = 1.f / (float)(c > 0 ? c : 1);    // max(count, 1)
    float4 r0, r1;
    r0.x = acc[0] * inv; r0.y = acc[1] * inv; r0.z = acc[2] * inv; r0.w = acc[3] * inv;
    r1.x = acc[4] * inv; r1.y = acc[5] * inv; r1.z = acc[6] * inv; r1.w = acc[7] * inv;
    float* op = out + (size_t)n * D + hsel * HD + sub * 8;
    *(float4*)(op)     = r0;
    *(float4*)(op + 4) = r1;
}

extern "C" void kernel_launch(void* const* d_in, const int* in_sizes, int n_in,
                              void* d_out, int out_size, void* d_ws, size_t ws_size,
                              hipStream_t stream) {
    const float* src   = (const float*)d_in[0];
    const int*   gidx  = (const int*)d_in[1];
    const int*   segid = (const int*)d_in[2];
    const int E = in_sizes[1];
    const int N = in_sizes[0] / D;       // == out_size / D

    // workspace layout: start[N+1] ints | hsrcA[N*16] | hsrcB[N*16] (fp16)
    char* ws = (char*)d_ws;
    int* start = (int*)ws;
    size_t off = ((size_t)(N + 1) * sizeof(int) + 255) & ~(size_t)255;
    _Float16* hsrcA = (_Float16*)(ws + off);
    off += ((size_t)N * HD * sizeof(_Float16) + 255) & ~(size_t)255;
    _Float16* hsrcB = (_Float16*)(ws + off);

    float* out = (float*)d_out;

    const int threadsA = (E + 1 > 2 * N) ? (E + 1) : (2 * N);
    const int blocksA = (threadsA + BLOCK - 1) / BLOCK;
    prep_kernel<<<blocksA, BLOCK, 0, stream>>>(src, segid, start, hsrcA, hsrcB, E, N);

    const int nblkHalf = (N + SEGS_PER_BLOCK - 1) / SEGS_PER_BLOCK;        // blocks per half
    const int blocksB  = ((2 * nblkHalf + 7) / 8) * 8;                     // >= nblkHalf per XCD-group
    AggregationLayer_53051436040325_kernel<<<blocksB, BLOCK, 0, stream>>>(
        hsrcA, hsrcB, gidx, start, out, N, nblkHalf);
}